// Round 21
// baseline (374.603 us; speedup 1.0000x reference)
//
#include <hip/hip_runtime.h>
#include <math.h>

#define N_NODES 51200
#define N_EDGES 640000
#define N_TYPES 4
#define N_RELS  8
#define N_HEADS 4
#define D_K     32
#define DIM     128
#define NODES_PER_TYPE (N_NODES / N_TYPES)   // 12800
#define EDGES_PER_REL  (N_EDGES / N_RELS)    // 80000
#define INV_SQRT_DK 0.17677669529663687f

typedef __attribute__((ext_vector_type(8))) short bf16x8;
typedef __attribute__((ext_vector_type(4))) float f32x4;

__device__ inline float bf2f(ushort u) {
    union { unsigned u; float f; } x; x.u = ((unsigned)u) << 16; return x.f;
}
__device__ inline ushort f2bf(float f) {
    union { float f; unsigned u; } x; x.f = f;
    unsigned r = x.u + 0x7FFF + ((x.u >> 16) & 1);
    return (ushort)(r >> 16);
}
__device__ inline bf16x8 pack8(ushort4 a, ushort4 b) {
    bf16x8 f;
    f[0]=(short)a.x; f[1]=(short)a.y; f[2]=(short)a.z; f[3]=(short)a.w;
    f[4]=(short)b.x; f[5]=(short)b.y; f[6]=(short)b.z; f[7]=(short)b.w;
    return f;
}
// global-memory fragment (split-half k layout)
__device__ inline bf16x8 ldfrag(const ushort* p) {
    return pack8(*(const ushort4*)p, *(const ushort4*)(p + 16));
}
// fragment from two uint2 (coalesced fragment-order Y)
__device__ inline bf16x8 packu(uint2 a, uint2 b) {
    bf16x8 f;
    f[0]=(short)(a.x & 0xffff); f[1]=(short)(a.x >> 16);
    f[2]=(short)(a.y & 0xffff); f[3]=(short)(a.y >> 16);
    f[4]=(short)(b.x & 0xffff); f[5]=(short)(b.x >> 16);
    f[6]=(short)(b.y & 0xffff); f[7]=(short)(b.y >> 16);
    return f;
}
// LDS fragment from a [rows][128]-ushort tile, XOR-swizzled: col ^ ((row&7)<<3)
__device__ inline bf16x8 ldsfragA(const ushort* S, int row, int c0) {
    const ushort* p0 = S + row * 128 + ((c0     ) ^ ((row & 7) << 3));
    const ushort* p1 = S + row * 128 + ((c0 + 16) ^ ((row & 7) << 3));
    return pack8(*(const ushort4*)p0, *(const ushort4*)p1);
}

__global__ __launch_bounds__(256) void zero_kernel(float* __restrict__ p, int n4) {
    int i = blockIdx.x * blockDim.x + threadIdx.x;
    if (i < n4) ((float4*)p)[i] = make_float4(0.f, 0.f, 0.f, 0.f);
}

__global__ __launch_bounds__(256) void cvt_h(const float* __restrict__ h, ushort* __restrict__ hb) {
    int i = blockIdx.x * 256 + threadIdx.x;
    float4 v = ((const float4*)h)[i];
    ushort4 o; o.x=f2bf(v.x); o.y=f2bf(v.y); o.z=f2bf(v.z); o.w=f2bf(v.w);
    ((ushort4*)hb)[i] = o;
}

// Transpose + bf16-convert weights. WT (ushort): WkT 0 | WqT 65536 | WvT 131072 |
// WaT 196608 | WattT 262144 | WmsgT 294912
__global__ __launch_bounds__(256) void prep_weights(
    const float* __restrict__ Wk, const float* __restrict__ Wq,
    const float* __restrict__ Wv, const float* __restrict__ Wa,
    const float* __restrict__ Watt, const float* __restrict__ Wmsg,
    ushort* __restrict__ WT)
{
    int g = blockIdx.x * 256 + threadIdx.x;
    if (g < 262144) {
        int which = g >> 16;
        int rem = g & 65535;
        int t = rem >> 14, idx = rem & 16383;
        int d = idx >> 7, o = idx & 127;
        const float* src = (which==0)?Wk:(which==1)?Wq:(which==2)?Wv:Wa;
        WT[(size_t)which*65536 + t*16384 + o*128 + d] = f2bf(src[t*16384 + d*128 + o]);
    } else {
        int g2 = g - 262144;
        int which = g2 >> 15;
        int rem = g2 & 32767;
        int rh = rem >> 10, idx = rem & 1023;
        int k = idx >> 5, j = idx & 31;
        const float* src = which ? Wmsg : Watt;
        WT[262144 + which*32768 + rh*1024 + j*32 + k] = f2bf(src[rh*1024 + k*32 + j]);
    }
}

// Fused K/Q/V projection: LDS-staged A and W (swizzled), C through LDS.
__global__ __launch_bounds__(256) void proj_fused(
    const ushort* __restrict__ hb, const ushort* __restrict__ WT,
    ushort* __restrict__ kb, ushort* __restrict__ qb, ushort* __restrict__ vb)
{
    __shared__ ushort As[64 * 128];
    __shared__ ushort Ws[128 * 128];
    const int tid = threadIdx.x;
    const int n0 = blockIdx.x * 64;
    const int t  = n0 / NODES_PER_TYPE;
    const int wv = tid >> 6, l = tid & 63;
    const int rc = l & 15, g = l >> 4, kg = g * 4;
    ushort* Cs = Ws;

    #pragma unroll
    for (int rd = 0; rd < 4; ++rd) {
        int f = tid + rd * 256;
        int row = f >> 4, cu = (f & 15) * 8;
        int4 x = *(const int4*)(hb + (size_t)(n0 + row) * DIM + cu);
        *(int4*)(As + row * 128 + (cu ^ ((row & 7) << 3))) = x;
    }
    {
        const ushort* Wsrc = WT + (size_t)t * 16384;
        #pragma unroll
        for (int rd = 0; rd < 8; ++rd) {
            int f = tid + rd * 256;
            int o = f >> 4, cu = (f & 15) * 8;
            int4 x = *(const int4*)(Wsrc + o * 128 + cu);
            *(int4*)(Ws + o * 128 + (cu ^ ((o & 7) << 3))) = x;
        }
    }
    __syncthreads();

    const int arow = wv * 16 + rc;
    bf16x8 af[4];
    #pragma unroll
    for (int kt = 0; kt < 4; ++kt) af[kt] = ldsfragA(As, arow, kt * 32 + kg);

    for (int which = 0; which < 3; ++which) {
        ushort* outp = (which == 0) ? kb : (which == 1) ? qb : vb;

        f32x4 acc[8];
        #pragma unroll
        for (int ct = 0; ct < 8; ++ct) {
            acc[ct][0]=0.f; acc[ct][1]=0.f; acc[ct][2]=0.f; acc[ct][3]=0.f;
            const int orow = ct * 16 + rc;
            #pragma unroll
            for (int kt = 0; kt < 4; ++kt)
                acc[ct] = __builtin_amdgcn_mfma_f32_16x16x32_bf16(
                    af[kt], ldsfragA(Ws, orow, kt * 32 + kg), acc[ct], 0, 0, 0);
        }
        __syncthreads();

        #pragma unroll
        for (int ct = 0; ct < 8; ++ct)
            #pragma unroll
            for (int i = 0; i < 4; ++i)
                Cs[(wv * 16 + g * 4 + i) * 136 + ct * 16 + rc] = f2bf(acc[ct][i]);
        __syncthreads();

        #pragma unroll
        for (int rd = 0; rd < 4; ++rd) {
            int f = tid + rd * 256;
            int row = f >> 4, cu = (f & 15) * 8;
            int4 x = *(const int4*)(Cs + row * 136 + cu);
            *(int4*)(outp + (size_t)(n0 + row) * DIM + cu) = x;
        }

        if (which < 2) {
            __syncthreads();
            const ushort* Wsrc = WT + (size_t)(which + 1) * 65536 + t * 16384;
            #pragma unroll
            for (int rd = 0; rd < 8; ++rd) {
                int f = tid + rd * 256;
                int o = f >> 4, cu = (f & 15) * 8;
                int4 x = *(const int4*)(Wsrc + o * 128 + cu);
                *(int4*)(Ws + o * 128 + (cu ^ ((o & 7) << 3))) = x;
            }
            __syncthreads();
        }
    }
}

// q-transform for FOUR relations per 64-node tile
__global__ __launch_bounds__(256) void trans4(
    const ushort* __restrict__ qb, const ushort* __restrict__ WattS,
    ushort* __restrict__ tf0, ushort* __restrict__ tf1,
    ushort* __restrict__ tf2, ushort* __restrict__ tf3)
{
    __shared__ ushort As[64 * 128];
    __shared__ ushort Ws[4096];
    __shared__ ushort Cs[64 * 136];
    const int tid = threadIdx.x;
    const int n0 = blockIdx.x * 64;
    const int wv = tid >> 6, l = tid & 63;
    const int rc = l & 15, g = l >> 4, kg = g * 4;
    ushort* tfs[4] = {tf0, tf1, tf2, tf3};

    #pragma unroll
    for (int rd = 0; rd < 4; ++rd) {
        int f = tid + rd * 256;
        int row = f >> 4, cu = (f & 15) * 8;
        int4 x = *(const int4*)(qb + (size_t)(n0 + row) * DIM + cu);
        *(int4*)(As + row * 128 + (cu ^ ((row & 7) << 3))) = x;
    }
    #pragma unroll
    for (int rd = 0; rd < 4; ++rd) {
        int f = tid + rd * 256;
        int idx = f * 4;
        ushort4 x = *(const ushort4*)(WattS + idx);
        *(ushort4*)(Ws + (idx ^ (((idx >> 5) & 7) << 2))) = x;
    }
    __syncthreads();

    const int arow = wv * 16 + rc;
    bf16x8 af[4];
    #pragma unroll
    for (int hh = 0; hh < 4; ++hh) af[hh] = ldsfragA(As, arow, hh * 32 + kg);

    for (int rr = 0; rr < 4; ++rr) {
        #pragma unroll
        for (int ct = 0; ct < 8; ++ct) {
            const int hh = ct >> 1, jb = (ct & 1) * 16;
            const int j = jb + rc;
            const int w0 = hh * 1024 + j * 32 + kg;
            bf16x8 bf = pack8(*(const ushort4*)(Ws + ( w0        ^ ((j & 7) << 2))),
                              *(const ushort4*)(Ws + ((w0 + 16)  ^ ((j & 7) << 2))));
            f32x4 acc = {0.f, 0.f, 0.f, 0.f};
            acc = __builtin_amdgcn_mfma_f32_16x16x32_bf16(af[hh], bf, acc, 0, 0, 0);
            const int col = hh * 32 + jb + rc;
            #pragma unroll
            for (int i = 0; i < 4; ++i)
                Cs[(wv * 16 + g * 4 + i) * 136 + col] = f2bf(acc[i]);
        }
        __syncthreads();

        #pragma unroll
        for (int rd = 0; rd < 4; ++rd) {
            int f = tid + rd * 256;
            int row = f >> 4, cu = (f & 15) * 8;
            int4 x = *(const int4*)(Cs + row * 136 + cu);
            *(int4*)(tfs[rr] + (size_t)(n0 + row) * DIM + cu) = x;
        }

        if (rr < 3) {
            __syncthreads();
            #pragma unroll
            for (int rd = 0; rd < 4; ++rd) {
                int f = tid + rd * 256;
                int idx = f * 4;
                ushort4 x = *(const ushort4*)(WattS + (rr + 1) * 4096 + idx);
                *(ushort4*)(Ws + (idx ^ (((idx >> 5) & 7) << 2))) = x;
            }
            __syncthreads();
        }
    }
}

// Edge score over FOUR relations in one wide dispatch (CSR order)
__global__ __launch_bounds__(256) void score4(
    const ushort* __restrict__ tf0, const ushort* __restrict__ tf1,
    const ushort* __restrict__ tf2, const ushort* __restrict__ tf3,
    const ushort* __restrict__ kb, const float* __restrict__ pri,
    const int* __restrict__ srcS, const int* __restrict__ dstS,
    float* __restrict__ evals, int r0)
{
    const int j = blockIdx.x / (EDGES_PER_REL / 32);
    const int b = blockIdx.x % (EDGES_PER_REL / 32);
    const ushort* tfb = (j == 0) ? tf0 : (j == 1) ? tf1 : (j == 2) ? tf2 : tf3;
    const int r = r0 + j;
    const int tid = threadIdx.x;
    const int lane = tid & 31;
    const int hh = lane >> 3;
    const int eslot = tid >> 5;
    const float prih = pri[r * N_HEADS + hh] * INV_SQRT_DK;
    int p = r * EDGES_PER_REL + b * 32 + eslot;
    #pragma unroll
    for (int it = 0; it < 4; ++it, p += 8) {
        const int src = srcS[p];
        const int dst = dstS[p];
        ushort4 ua = *(const ushort4*)(tfb + (size_t)dst * DIM + lane * 4);
        ushort4 ub = *(const ushort4*)(kb  + (size_t)src * DIM + lane * 4);
        float s = bf2f(ua.x)*bf2f(ub.x) + bf2f(ua.y)*bf2f(ub.y)
                + bf2f(ua.z)*bf2f(ub.z) + bf2f(ua.w)*bf2f(ub.w);
        s += __shfl_xor(s, 1);
        s += __shfl_xor(s, 2);
        s += __shfl_xor(s, 4);
        if ((lane & 7) == 0)
            evals[(size_t)p * N_HEADS + hh] = expf(s * prih);
    }
}

// ---------------- CSR build over (rel, dst) buckets ----------------

__global__ __launch_bounds__(256) void hist_kernel(
    const int* __restrict__ col, int* __restrict__ cnt)
{
    int e = blockIdx.x * 256 + threadIdx.x;
    int r = (unsigned)e / EDGES_PER_REL;
    atomicAdd(&cnt[r * N_NODES + col[e]], 1);
}

__global__ __launch_bounds__(256) void scan1_kernel(
    const int* __restrict__ cnt, int* __restrict__ off, int* __restrict__ bsum)
{
    __shared__ int s[256];
    int g = blockIdx.x * 256 + threadIdx.x;
    int v = cnt[g];
    s[threadIdx.x] = v;
    __syncthreads();
    #pragma unroll
    for (int d = 1; d < 256; d <<= 1) {
        int t = (threadIdx.x >= d) ? s[threadIdx.x - d] : 0;
        __syncthreads();
        s[threadIdx.x] += t;
        __syncthreads();
    }
    off[g] = s[threadIdx.x] - v;
    if (threadIdx.x == 255) bsum[blockIdx.x] = s[255];
}

__global__ __launch_bounds__(256) void scan2_kernel(int* __restrict__ bsum, int nb)
{
    __shared__ int s[256];
    __shared__ int carry;
    const int tid = threadIdx.x;
    if (tid == 0) carry = 0;
    __syncthreads();
    for (int base = 0; base < nb; base += 256) {
        int i = base + tid;
        int v = (i < nb) ? bsum[i] : 0;
        s[tid] = v;
        __syncthreads();
        #pragma unroll
        for (int d = 1; d < 256; d <<= 1) {
            int t = (tid >= d) ? s[tid - d] : 0;
            __syncthreads();
            s[tid] += t;
            __syncthreads();
        }
        int incl = s[tid];
        if (i < nb) bsum[i] = carry + incl - v;
        __syncthreads();
        if (tid == 255) carry += incl;
        __syncthreads();
    }
}

__global__ __launch_bounds__(256) void scan3_kernel(
    int* __restrict__ off, const int* __restrict__ bsum, int* __restrict__ cursor)
{
    int g = blockIdx.x * 256 + threadIdx.x;
    int o = off[g] + bsum[blockIdx.x];
    off[g] = o;
    cursor[g] = o;
}

__global__ __launch_bounds__(256) void scatter_kernel(
    const int* __restrict__ row, const int* __restrict__ col,
    int* __restrict__ cursor, int* __restrict__ srcS, int* __restrict__ dstS)
{
    int e = blockIdx.x * 256 + threadIdx.x;
    int r = (unsigned)e / EDGES_PER_REL;
    int c = col[e];
    int pos = atomicAdd(&cursor[r * N_NODES + c], 1);
    srcS[pos] = row[e];
    dstS[pos] = c;
}

__global__ __launch_bounds__(256) void denom_pull(
    const int* __restrict__ off, const int* __restrict__ cnt,
    const float* __restrict__ evals, float* __restrict__ den)
{
    int g = blockIdx.x * 256 + threadIdx.x;
    int n = g >> 2, hh = g & 3;
    float s = 0.f;
    #pragma unroll
    for (int r = 0; r < N_RELS; ++r) {
        int b = off[r * N_NODES + n];
        int m = cnt[r * N_NODES + n];
        for (int i = 0; i < m; ++i)
            s += evals[(size_t)(b + i) * 4 + hh];
    }
    den[g] = s;
}

// Y_r in FRAGMENT-ORDER layout: uint for col-pair cp of node n goes to
// ((tile*4+hh)*2 + half)*128 + (lg*16 + (n&15))*2 + sel   (uint units)
// where tile=n>>4, cpl=cp&15, half=cpl>>3, lg=(cpl&7)>>1, sel=cpl&1.
__global__ __launch_bounds__(256) void ypull(
    const ushort* __restrict__ vb,
    const int* __restrict__ srcS,
    const int* __restrict__ off, const int* __restrict__ cnt,
    const float* __restrict__ evals, const float* __restrict__ den,
    ushort* __restrict__ Y0, ushort* __restrict__ Y1,
    ushort* __restrict__ Y2, ushort* __restrict__ Y3, int r0)
{
    const int tid = threadIdx.x;
    const int n = blockIdx.x * 4 + (tid >> 6);
    const int lane = tid & 63;            // d-pair (col-pair) index
    const int hh = lane >> 4;
    const float rden = 1.f / (den[(size_t)n * 4 + hh] + 1e-16f);
    const uint* vb2 = (const uint*)vb;
    ushort* Ys[4] = {Y0, Y1, Y2, Y3};
    // fragment-order destination index
    const int cpl = lane & 15;
    const int half = cpl >> 3, lg = (cpl & 7) >> 1, sel = cpl & 1;
    const size_t yidx = ((size_t)((n >> 4) * 4 + hh) * 2 + half) * 128
                      + (lg * 16 + (n & 15)) * 2 + sel;
    #pragma unroll 4
    for (int rr = 0; rr < 4; ++rr) {
        const int b = off[(r0 + rr) * N_NODES + n];
        const int m = cnt[(r0 + rr) * N_NODES + n];
        float ax = 0.f, ay = 0.f;
        int i = 0;
        for (; i + 2 <= m; i += 2) {
            const int p0 = b + i, p1 = b + i + 1;
            const float e0 = evals[(size_t)p0 * 4 + hh];
            const float e1 = evals[(size_t)p1 * 4 + hh];
            const uint w0 = vb2[((size_t)srcS[p0] << 6) + lane];
            const uint w1 = vb2[((size_t)srcS[p1] << 6) + lane];
            ax = fmaf(e0, bf2f((ushort)(w0 & 0xffff)), ax);
            ay = fmaf(e0, bf2f((ushort)(w0 >> 16)), ay);
            ax = fmaf(e1, bf2f((ushort)(w1 & 0xffff)), ax);
            ay = fmaf(e1, bf2f((ushort)(w1 >> 16)), ay);
        }
        if (i < m) {
            const int p0 = b + i;
            const float e0 = evals[(size_t)p0 * 4 + hh];
            const uint w0 = vb2[((size_t)srcS[p0] << 6) + lane];
            ax = fmaf(e0, bf2f((ushort)(w0 & 0xffff)), ax);
            ay = fmaf(e0, bf2f((ushort)(w0 >> 16)), ay);
        }
        uint o = (uint)f2bf(ax * rden) | ((uint)f2bf(ay * rden) << 16);
        ((uint*)Ys[rr])[yidx] = o;
    }
}

// U = sum_{rr<4} Y_rr @ Wmsg[rr]. 16-node tiles; wave = head. Coalesced
// fragment-order Y loads (uint2 per half).
__global__ __launch_bounds__(256) void agg_gemm(
    const ushort* __restrict__ Y0, const ushort* __restrict__ Y1,
    const ushort* __restrict__ Y2, const ushort* __restrict__ Y3,
    const ushort* __restrict__ WmsgT, int r0, float* __restrict__ U)
{
    const int tid = threadIdx.x;
    const int wc = tid >> 6;             // wave = head
    const int l = tid & 63;
    const int rc = l & 15, kg = (l >> 4) * 4;
    const ushort* Ys[4] = {Y0, Y1, Y2, Y3};
    const size_t ybase = ((size_t)blockIdx.x * 4 + wc) * 2 * 64;  // uint2 units
    float* Ut = U + (size_t)blockIdx.x * 2048;

    bf16x8 af4[4];
    #pragma unroll
    for (int rr = 0; rr < 4; ++rr) {
        const uint2* Yf = (const uint2*)Ys[rr];
        af4[rr] = packu(Yf[ybase + l], Yf[ybase + 64 + l]);
    }
    #pragma unroll
    for (int jb2 = 0; jb2 < 2; ++jb2) {
        const int jb = jb2 * 16;
        f32x4 acc = {0.f, 0.f, 0.f, 0.f};
        #pragma unroll
        for (int rr = 0; rr < 4; ++rr) {
            const ushort* Bcol = WmsgT + (size_t)(r0+rr)*4096 + wc*1024 + (size_t)(jb + rc) * 32 + kg;
            acc = __builtin_amdgcn_mfma_f32_16x16x32_bf16(af4[rr], ldfrag(Bcol), acc, 0, 0, 0);
        }
        #pragma unroll
        for (int i = 0; i < 4; ++i)
            Ut[jb2 * 1024 + i * 256 + tid] = acc[i];
    }
}

// Pass B fused with output projection. 16-node tiles; coalesced Y loads.
__global__ __launch_bounds__(256) void gemm_out(
    const ushort* __restrict__ Y0, const ushort* __restrict__ Y1,
    const ushort* __restrict__ Y2, const ushort* __restrict__ Y3,
    const ushort* __restrict__ WT, const float* __restrict__ U,
    const float* __restrict__ skip, float* __restrict__ outp, int r0)
{
    __shared__ float CsF[16 * 132];          // 8.4 KB; first 4 KB aliased as bf16 Ab
    ushort* Ab = (ushort*)CsF;
    const int tid = threadIdx.x;
    const int n0 = blockIdx.x * 16;
    const int t  = n0 / NODES_PER_TYPE;
    const int wc = tid >> 6;             // wave = head / col quarter
    const int l = tid & 63;
    const int rc = l & 15, g = l >> 4, kg = g * 4;
    const ushort* Ys[4] = {Y0, Y1, Y2, Y3};
    const size_t ybase = ((size_t)blockIdx.x * 4 + wc) * 2 * 64;  // uint2 units
    const float sg = 1.f / (1.f + expf(-skip[t]));
    const float* Ut = U + (size_t)blockIdx.x * 2048;

    // phase 1: finish U' (this wave: 16 rows x head-wc's 32 cols)
    f32x4 acc[2];
    bf16x8 af4[4];
    #pragma unroll
    for (int rr = 0; rr < 4; ++rr) {
        const uint2* Yf = (const uint2*)Ys[rr];
        af4[rr] = packu(Yf[ybase + l], Yf[ybase + 64 + l]);
    }
    #pragma unroll
    for (int jb2 = 0; jb2 < 2; ++jb2) {
        const int jb = jb2 * 16;
        #pragma unroll
        for (int i = 0; i < 4; ++i)
            acc[jb2][i] = Ut[jb2 * 1024 + i * 256 + tid];
        #pragma unroll
        for (int rr = 0; rr < 4; ++rr) {
            const ushort* Bcol = WT + 294912 + (size_t)(r0+rr)*4096 + wc*1024 + (size_t)(jb + rc) * 32 + kg;
            acc[jb2] = __builtin_amdgcn_mfma_f32_16x16x32_bf16(af4[rr], ldfrag(Bcol), acc[jb2], 0, 0, 0);
        }
    }

    // phase 2: acc -> bf16 swizzled Ab tile [16][128]
    #pragma unroll
    for (int jb2 = 0; jb2 < 2; ++jb2) {
        const int col = wc * 32 + jb2 * 16 + rc;
        #pragma unroll
        for (int i = 0; i < 4; ++i) {
            const int row = g * 4 + i;
            Ab[row * 128 + (col ^ ((row & 7) << 3))] = f2bf(acc[jb2][i]);
        }
    }
    __syncthreads();

    // phase 3: output projection; this wave computes cols wc*32..wc*32+31
    bf16x8 af[4];
    #pragma unroll
    for (int kt = 0; kt < 4; ++kt) af[kt] = ldsfragA(Ab, rc, kt * 32 + kg);
    const ushort* Wb = WT + 196608 + (size_t)t * 16384;
    f32x4 acc2[2];
    #pragma unroll
    for (int jb2 = 0; jb2 < 2; ++jb2) {
        acc2[jb2][0]=0.f; acc2[jb2][1]=0.f; acc2[jb2][2]=0.f; acc2[jb2][3]=0.f;
        const int colg = wc * 32 + jb2 * 16 + rc;
        const ushort* Bcol = Wb + (size_t)colg * 128 + kg;
        #pragma unroll
        for (int kt = 0; kt < 4; ++kt)
            acc2[jb2] = __builtin_amdgcn_mfma_f32_16x16x32_bf16(
                af[kt], ldfrag(Bcol + kt * 32), acc2[jb2], 0, 0, 0);
    }
    __syncthreads();   // Ab reads done before fp32 overwrite

    // phase 4: acc2*sg -> fp32 LDS [16][132] -> coalesced stores
    #pragma unroll
    for (int jb2 = 0; jb2 < 2; ++jb2) {
        const int col = wc * 32 + jb2 * 16 + rc;
        #pragma unroll
        for (int i = 0; i < 4; ++i)
            CsF[(g * 4 + i) * 132 + col] = sg * acc2[jb2][i];
    }
    __syncthreads();

    #pragma unroll
    for (int rd = 0; rd < 2; ++rd) {
        int f = tid + rd * 256;
        int row = f >> 5, c4 = (f & 31) * 4;
        float4 x = *(const float4*)&CsF[row * 132 + c4];
        *(float4*)(outp + (size_t)(n0 + row) * DIM + c4) = x;
    }
}

extern "C" void kernel_launch(void* const* d_in, const int* in_sizes, int n_in,
                              void* d_out, int out_size, void* d_ws, size_t ws_size,
                              hipStream_t stream) {
    (void)in_sizes; (void)n_in; (void)out_size; (void)ws_size;
    const float* h    = (const float*)d_in[0];
    const float* Wk   = (const float*)d_in[1];
    const float* Wq   = (const float*)d_in[2];
    const float* Wv   = (const float*)d_in[3];
    const float* Wa   = (const float*)d_in[4];
    const float* Watt = (const float*)d_in[5];
    const float* Wmsg = (const float*)d_in[6];
    const float* pri  = (const float*)d_in[7];
    const float* skip = (const float*)d_in[8];
    const int* row_idx = (const int*)d_in[9];
    const int* col_idx = (const int*)d_in[10];

    float* out = (float*)d_out;
    char*  wsb = (char*)d_ws;

    const size_t BF = (size_t)N_NODES * DIM * 2;   // 13.107 MB per bf16 node array
    // ws map (proven 8*BF = 104.86 MB):
    //  slot0: hb -> tfA0 (score) -> Y0 | slot1: kb -> Y1 | slot2: vb
    //  slot3: qb -> Y2 | slot4: tfb=tfA1 -> Y3
    //  slot5-6: tfA2, tfA3 (score phase) then U (fragment-order fp32, 26.2 MB)
    //  slot7: WT (0.66 MB)
    ushort* hb  = (ushort*)(wsb);
    ushort* kb  = (ushort*)(wsb + BF);
    ushort* vb  = (ushort*)(wsb + 2*BF);
    ushort* qb  = (ushort*)(wsb + 3*BF);
    ushort* tfb = (ushort*)(wsb + 4*BF);
    ushort* tf2 = (ushort*)(wsb + 5*BF);
    ushort* tf3 = (ushort*)(wsb + 6*BF);
    float*  U   = (float*) (wsb + 5*BF);
    ushort* WT  = (ushort*)(wsb + 7*BF);
    ushort* WattT = WT + 262144;
    ushort* WmsgT = WT + 294912;

    // d_out staging (fully consumed before gemm_out overwrites):
    float* evals = out;
    float* den   = out + (size_t)N_EDGES * N_HEADS;
    int*   cnt    = (int*)(den + (size_t)N_NODES * N_HEADS);
    int*   off    = cnt + (size_t)N_RELS * N_NODES;
    int*   bsum   = off + (size_t)N_RELS * N_NODES;
    int*   cursor = bsum + 1600;
    int*   srcS   = cursor + (size_t)N_RELS * N_NODES;
    int*   dstS   = srcS + N_EDGES;
    const int NBUCK = N_RELS * N_NODES;

    // 1. weight prep + h conversion + zero counts
    prep_weights<<<1280, 256, 0, stream>>>(Wk, Wq, Wv, Wa, Watt, Wmsg, WT);
    cvt_h<<<(N_NODES * DIM / 4) / 256, 256, 0, stream>>>(h, hb);
    zero_kernel<<<NBUCK / 4 / 256, 256, 0, stream>>>((float*)cnt, NBUCK / 4);
    // 2. fused K/Q/V projection
    proj_fused<<<N_NODES / 64, 256, 0, stream>>>(hb, WT, kb, qb, vb);
    // 3. CSR build + sorted src/dst
    hist_kernel<<<N_EDGES / 256, 256, 0, stream>>>(col_idx, cnt);
    scan1_kernel<<<NBUCK / 256, 256, 0, stream>>>(cnt, off, bsum);
    scan2_kernel<<<1, 256, 0, stream>>>(bsum, NBUCK / 256);
    scan3_kernel<<<NBUCK / 256, 256, 0, stream>>>(off, bsum, cursor);
    scatter_kernel<<<N_EDGES / 256, 256, 0, stream>>>(row_idx, col_idx, cursor, srcS, dstS);
    // 4. score phase: two 4-relation waves {trans4 -> wide score4}
    trans4<<<N_NODES / 64, 256, 0, stream>>>(qb, WattT, hb, tfb, tf2, tf3);
    score4<<<4 * (EDGES_PER_REL / 32), 256, 0, stream>>>(
        hb, tfb, tf2, tf3, kb, pri, srcS, dstS, evals, 0);
    trans4<<<N_NODES / 64, 256, 0, stream>>>(qb, WattT + 4 * 4096, hb, tfb, tf2, tf3);
    score4<<<4 * (EDGES_PER_REL / 32), 256, 0, stream>>>(
        hb, tfb, tf2, tf3, kb, pri, srcS, dstS, evals, 4);
    // 5. softmax denominators
    denom_pull<<<N_NODES * N_HEADS / 256, 256, 0, stream>>>(off, cnt, evals, den);
    // 6. aggregation: pass A -> U; pass B + output projection -> out
    ypull<<<N_NODES / 4, 256, 0, stream>>>(vb, srcS, off, cnt, evals, den,
                                           hb, kb, qb, tfb, 0);
    agg_gemm<<<N_NODES / 16, 256, 0, stream>>>(hb, kb, qb, tfb, WmsgT, 0, U);
    ypull<<<N_NODES / 4, 256, 0, stream>>>(vb, srcS, off, cnt, evals, den,
                                           hb, kb, qb, tfb, 4);
    gemm_out<<<N_NODES / 16, 256, 0, stream>>>(hb, kb, qb, tfb, WT, U, skip, out, 4);
}

// Round 22
// 360.314 us; speedup vs baseline: 1.0397x; 1.0397x over previous
//
#include <hip/hip_runtime.h>
#include <math.h>

#define N_NODES 51200
#define N_EDGES 640000
#define N_TYPES 4
#define N_RELS  8
#define N_HEADS 4
#define D_K     32
#define DIM     128
#define NODES_PER_TYPE (N_NODES / N_TYPES)   // 12800
#define EDGES_PER_REL  (N_EDGES / N_RELS)    // 80000
#define INV_SQRT_DK 0.17677669529663687f

typedef __attribute__((ext_vector_type(8))) short bf16x8;
typedef __attribute__((ext_vector_type(4))) float f32x4;

__device__ inline float bf2f(ushort u) {
    union { unsigned u; float f; } x; x.u = ((unsigned)u) << 16; return x.f;
}
__device__ inline ushort f2bf(float f) {
    union { float f; unsigned u; } x; x.f = f;
    unsigned r = x.u + 0x7FFF + ((x.u >> 16) & 1);
    return (ushort)(r >> 16);
}
__device__ inline bf16x8 pack8(ushort4 a, ushort4 b) {
    bf16x8 f;
    f[0]=(short)a.x; f[1]=(short)a.y; f[2]=(short)a.z; f[3]=(short)a.w;
    f[4]=(short)b.x; f[5]=(short)b.y; f[6]=(short)b.z; f[7]=(short)b.w;
    return f;
}
// global-memory fragment (split-half k layout)
__device__ inline bf16x8 ldfrag(const ushort* p) {
    return pack8(*(const ushort4*)p, *(const ushort4*)(p + 16));
}
// LDS fragment from a [rows][128]-ushort tile, XOR-swizzled: col ^ ((row&7)<<3)
__device__ inline bf16x8 ldsfragA(const ushort* S, int row, int c0) {
    const ushort* p0 = S + row * 128 + ((c0     ) ^ ((row & 7) << 3));
    const ushort* p1 = S + row * 128 + ((c0 + 16) ^ ((row & 7) << 3));
    return pack8(*(const ushort4*)p0, *(const ushort4*)p1);
}

__global__ __launch_bounds__(256) void zero_kernel(float* __restrict__ p, int n4) {
    int i = blockIdx.x * blockDim.x + threadIdx.x;
    if (i < n4) ((float4*)p)[i] = make_float4(0.f, 0.f, 0.f, 0.f);
}

__global__ __launch_bounds__(256) void cvt_h(const float* __restrict__ h, ushort* __restrict__ hb) {
    int i = blockIdx.x * 256 + threadIdx.x;
    float4 v = ((const float4*)h)[i];
    ushort4 o; o.x=f2bf(v.x); o.y=f2bf(v.y); o.z=f2bf(v.z); o.w=f2bf(v.w);
    ((ushort4*)hb)[i] = o;
}

// Transpose + bf16-convert weights. WT (ushort): WkT 0 | WqT 65536 | WvT 131072 |
// WaT 196608 | WattT 262144 | WmsgT 294912
__global__ __launch_bounds__(256) void prep_weights(
    const float* __restrict__ Wk, const float* __restrict__ Wq,
    const float* __restrict__ Wv, const float* __restrict__ Wa,
    const float* __restrict__ Watt, const float* __restrict__ Wmsg,
    ushort* __restrict__ WT)
{
    int g = blockIdx.x * 256 + threadIdx.x;
    if (g < 262144) {
        int which = g >> 16;
        int rem = g & 65535;
        int t = rem >> 14, idx = rem & 16383;
        int d = idx >> 7, o = idx & 127;
        const float* src = (which==0)?Wk:(which==1)?Wq:(which==2)?Wv:Wa;
        WT[(size_t)which*65536 + t*16384 + o*128 + d] = f2bf(src[t*16384 + d*128 + o]);
    } else {
        int g2 = g - 262144;
        int which = g2 >> 15;
        int rem = g2 & 32767;
        int rh = rem >> 10, idx = rem & 1023;
        int k = idx >> 5, j = idx & 31;
        const float* src = which ? Wmsg : Watt;
        WT[262144 + which*32768 + rh*1024 + j*32 + k] = f2bf(src[rh*1024 + k*32 + j]);
    }
}

// Fused K/Q/V projection: LDS-staged A and W (swizzled), C through LDS.
__global__ __launch_bounds__(256) void proj_fused(
    const ushort* __restrict__ hb, const ushort* __restrict__ WT,
    ushort* __restrict__ kb, ushort* __restrict__ qb, ushort* __restrict__ vb)
{
    __shared__ ushort As[64 * 128];
    __shared__ ushort Ws[128 * 128];
    const int tid = threadIdx.x;
    const int n0 = blockIdx.x * 64;
    const int t  = n0 / NODES_PER_TYPE;
    const int wv = tid >> 6, l = tid & 63;
    const int rc = l & 15, g = l >> 4, kg = g * 4;
    ushort* Cs = Ws;

    #pragma unroll
    for (int rd = 0; rd < 4; ++rd) {
        int f = tid + rd * 256;
        int row = f >> 4, cu = (f & 15) * 8;
        int4 x = *(const int4*)(hb + (size_t)(n0 + row) * DIM + cu);
        *(int4*)(As + row * 128 + (cu ^ ((row & 7) << 3))) = x;
    }
    {
        const ushort* Wsrc = WT + (size_t)t * 16384;
        #pragma unroll
        for (int rd = 0; rd < 8; ++rd) {
            int f = tid + rd * 256;
            int o = f >> 4, cu = (f & 15) * 8;
            int4 x = *(const int4*)(Wsrc + o * 128 + cu);
            *(int4*)(Ws + o * 128 + (cu ^ ((o & 7) << 3))) = x;
        }
    }
    __syncthreads();

    const int arow = wv * 16 + rc;
    bf16x8 af[4];
    #pragma unroll
    for (int kt = 0; kt < 4; ++kt) af[kt] = ldsfragA(As, arow, kt * 32 + kg);

    for (int which = 0; which < 3; ++which) {
        ushort* outp = (which == 0) ? kb : (which == 1) ? qb : vb;

        f32x4 acc[8];
        #pragma unroll
        for (int ct = 0; ct < 8; ++ct) {
            acc[ct][0]=0.f; acc[ct][1]=0.f; acc[ct][2]=0.f; acc[ct][3]=0.f;
            const int orow = ct * 16 + rc;
            #pragma unroll
            for (int kt = 0; kt < 4; ++kt)
                acc[ct] = __builtin_amdgcn_mfma_f32_16x16x32_bf16(
                    af[kt], ldsfragA(Ws, orow, kt * 32 + kg), acc[ct], 0, 0, 0);
        }
        __syncthreads();

        #pragma unroll
        for (int ct = 0; ct < 8; ++ct)
            #pragma unroll
            for (int i = 0; i < 4; ++i)
                Cs[(wv * 16 + g * 4 + i) * 136 + ct * 16 + rc] = f2bf(acc[ct][i]);
        __syncthreads();

        #pragma unroll
        for (int rd = 0; rd < 4; ++rd) {
            int f = tid + rd * 256;
            int row = f >> 4, cu = (f & 15) * 8;
            int4 x = *(const int4*)(Cs + row * 136 + cu);
            *(int4*)(outp + (size_t)(n0 + row) * DIM + cu) = x;
        }

        if (which < 2) {
            __syncthreads();
            const ushort* Wsrc = WT + (size_t)(which + 1) * 65536 + t * 16384;
            #pragma unroll
            for (int rd = 0; rd < 8; ++rd) {
                int f = tid + rd * 256;
                int o = f >> 4, cu = (f & 15) * 8;
                int4 x = *(const int4*)(Wsrc + o * 128 + cu);
                *(int4*)(Ws + o * 128 + (cu ^ ((o & 7) << 3))) = x;
            }
            __syncthreads();
        }
    }
}

// q-transform for FOUR relations per 64-node tile
__global__ __launch_bounds__(256) void trans4(
    const ushort* __restrict__ qb, const ushort* __restrict__ WattS,
    ushort* __restrict__ tf0, ushort* __restrict__ tf1,
    ushort* __restrict__ tf2, ushort* __restrict__ tf3)
{
    __shared__ ushort As[64 * 128];
    __shared__ ushort Ws[4096];
    __shared__ ushort Cs[64 * 136];
    const int tid = threadIdx.x;
    const int n0 = blockIdx.x * 64;
    const int wv = tid >> 6, l = tid & 63;
    const int rc = l & 15, g = l >> 4, kg = g * 4;
    ushort* tfs[4] = {tf0, tf1, tf2, tf3};

    #pragma unroll
    for (int rd = 0; rd < 4; ++rd) {
        int f = tid + rd * 256;
        int row = f >> 4, cu = (f & 15) * 8;
        int4 x = *(const int4*)(qb + (size_t)(n0 + row) * DIM + cu);
        *(int4*)(As + row * 128 + (cu ^ ((row & 7) << 3))) = x;
    }
    #pragma unroll
    for (int rd = 0; rd < 4; ++rd) {
        int f = tid + rd * 256;
        int idx = f * 4;
        ushort4 x = *(const ushort4*)(WattS + idx);
        *(ushort4*)(Ws + (idx ^ (((idx >> 5) & 7) << 2))) = x;
    }
    __syncthreads();

    const int arow = wv * 16 + rc;
    bf16x8 af[4];
    #pragma unroll
    for (int hh = 0; hh < 4; ++hh) af[hh] = ldsfragA(As, arow, hh * 32 + kg);

    for (int rr = 0; rr < 4; ++rr) {
        #pragma unroll
        for (int ct = 0; ct < 8; ++ct) {
            const int hh = ct >> 1, jb = (ct & 1) * 16;
            const int j = jb + rc;
            const int w0 = hh * 1024 + j * 32 + kg;
            bf16x8 bf = pack8(*(const ushort4*)(Ws + ( w0        ^ ((j & 7) << 2))),
                              *(const ushort4*)(Ws + ((w0 + 16)  ^ ((j & 7) << 2))));
            f32x4 acc = {0.f, 0.f, 0.f, 0.f};
            acc = __builtin_amdgcn_mfma_f32_16x16x32_bf16(af[hh], bf, acc, 0, 0, 0);
            const int col = hh * 32 + jb + rc;
            #pragma unroll
            for (int i = 0; i < 4; ++i)
                Cs[(wv * 16 + g * 4 + i) * 136 + col] = f2bf(acc[i]);
        }
        __syncthreads();

        #pragma unroll
        for (int rd = 0; rd < 4; ++rd) {
            int f = tid + rd * 256;
            int row = f >> 4, cu = (f & 15) * 8;
            int4 x = *(const int4*)(Cs + row * 136 + cu);
            *(int4*)(tfs[rr] + (size_t)(n0 + row) * DIM + cu) = x;
        }

        if (rr < 3) {
            __syncthreads();
            #pragma unroll
            for (int rd = 0; rd < 4; ++rd) {
                int f = tid + rd * 256;
                int idx = f * 4;
                ushort4 x = *(const ushort4*)(WattS + (rr + 1) * 4096 + idx);
                *(ushort4*)(Ws + (idx ^ (((idx >> 5) & 7) << 2))) = x;
            }
            __syncthreads();
        }
    }
}

// Edge score over FOUR relations in one wide dispatch (CSR order)
__global__ __launch_bounds__(256) void score4(
    const ushort* __restrict__ tf0, const ushort* __restrict__ tf1,
    const ushort* __restrict__ tf2, const ushort* __restrict__ tf3,
    const ushort* __restrict__ kb, const float* __restrict__ pri,
    const int* __restrict__ srcS, const int* __restrict__ dstS,
    float* __restrict__ evals, int r0)
{
    const int j = blockIdx.x / (EDGES_PER_REL / 32);
    const int b = blockIdx.x % (EDGES_PER_REL / 32);
    const ushort* tfb = (j == 0) ? tf0 : (j == 1) ? tf1 : (j == 2) ? tf2 : tf3;
    const int r = r0 + j;
    const int tid = threadIdx.x;
    const int lane = tid & 31;
    const int hh = lane >> 3;
    const int eslot = tid >> 5;
    const float prih = pri[r * N_HEADS + hh] * INV_SQRT_DK;
    int p = r * EDGES_PER_REL + b * 32 + eslot;
    #pragma unroll
    for (int it = 0; it < 4; ++it, p += 8) {
        const int src = srcS[p];
        const int dst = dstS[p];
        ushort4 ua = *(const ushort4*)(tfb + (size_t)dst * DIM + lane * 4);
        ushort4 ub = *(const ushort4*)(kb  + (size_t)src * DIM + lane * 4);
        float s = bf2f(ua.x)*bf2f(ub.x) + bf2f(ua.y)*bf2f(ub.y)
                + bf2f(ua.z)*bf2f(ub.z) + bf2f(ua.w)*bf2f(ub.w);
        s += __shfl_xor(s, 1);
        s += __shfl_xor(s, 2);
        s += __shfl_xor(s, 4);
        if ((lane & 7) == 0)
            evals[(size_t)p * N_HEADS + hh] = expf(s * prih);
    }
}

// ---------------- CSR build over (rel, dst) buckets ----------------

__global__ __launch_bounds__(256) void hist_kernel(
    const int* __restrict__ col, int* __restrict__ cnt)
{
    int e = blockIdx.x * 256 + threadIdx.x;
    int r = (unsigned)e / EDGES_PER_REL;
    atomicAdd(&cnt[r * N_NODES + col[e]], 1);
}

__global__ __launch_bounds__(256) void scan1_kernel(
    const int* __restrict__ cnt, int* __restrict__ off, int* __restrict__ bsum)
{
    __shared__ int s[256];
    int g = blockIdx.x * 256 + threadIdx.x;
    int v = cnt[g];
    s[threadIdx.x] = v;
    __syncthreads();
    #pragma unroll
    for (int d = 1; d < 256; d <<= 1) {
        int t = (threadIdx.x >= d) ? s[threadIdx.x - d] : 0;
        __syncthreads();
        s[threadIdx.x] += t;
        __syncthreads();
    }
    off[g] = s[threadIdx.x] - v;
    if (threadIdx.x == 255) bsum[blockIdx.x] = s[255];
}

__global__ __launch_bounds__(256) void scan2_kernel(int* __restrict__ bsum, int nb)
{
    __shared__ int s[256];
    __shared__ int carry;
    const int tid = threadIdx.x;
    if (tid == 0) carry = 0;
    __syncthreads();
    for (int base = 0; base < nb; base += 256) {
        int i = base + tid;
        int v = (i < nb) ? bsum[i] : 0;
        s[tid] = v;
        __syncthreads();
        #pragma unroll
        for (int d = 1; d < 256; d <<= 1) {
            int t = (tid >= d) ? s[tid - d] : 0;
            __syncthreads();
            s[tid] += t;
            __syncthreads();
        }
        int incl = s[tid];
        if (i < nb) bsum[i] = carry + incl - v;
        __syncthreads();
        if (tid == 255) carry += incl;
        __syncthreads();
    }
}

__global__ __launch_bounds__(256) void scan3_kernel(
    int* __restrict__ off, const int* __restrict__ bsum, int* __restrict__ cursor)
{
    int g = blockIdx.x * 256 + threadIdx.x;
    int o = off[g] + bsum[blockIdx.x];
    off[g] = o;
    cursor[g] = o;
}

__global__ __launch_bounds__(256) void scatter_kernel(
    const int* __restrict__ row, const int* __restrict__ col,
    int* __restrict__ cursor, int* __restrict__ srcS, int* __restrict__ dstS)
{
    int e = blockIdx.x * 256 + threadIdx.x;
    int r = (unsigned)e / EDGES_PER_REL;
    int c = col[e];
    int pos = atomicAdd(&cursor[r * N_NODES + c], 1);
    srcS[pos] = row[e];
    dstS[pos] = c;
}

__global__ __launch_bounds__(256) void denom_pull(
    const int* __restrict__ off, const int* __restrict__ cnt,
    const float* __restrict__ evals, float* __restrict__ den)
{
    int g = blockIdx.x * 256 + threadIdx.x;
    int n = g >> 2, hh = g & 3;
    float s = 0.f;
    #pragma unroll
    for (int r = 0; r < N_RELS; ++r) {
        int b = off[r * N_NODES + n];
        int m = cnt[r * N_NODES + n];
        for (int i = 0; i < m; ++i)
            s += evals[(size_t)(b + i) * 4 + hh];
    }
    den[g] = s;
}

// Y_r[n][d] = (1/den) * sum_{p in bucket(r,n)} ev_p * v[src_p][d]
__global__ __launch_bounds__(256) void ypull(
    const ushort* __restrict__ vb,
    const int* __restrict__ srcS,
    const int* __restrict__ off, const int* __restrict__ cnt,
    const float* __restrict__ evals, const float* __restrict__ den,
    ushort* __restrict__ Y0, ushort* __restrict__ Y1,
    ushort* __restrict__ Y2, ushort* __restrict__ Y3, int r0)
{
    const int tid = threadIdx.x;
    const int n = blockIdx.x * 4 + (tid >> 6);
    const int lane = tid & 63;            // d-pair index
    const int hh = lane >> 4;
    const float rden = 1.f / (den[(size_t)n * 4 + hh] + 1e-16f);
    const uint* vb2 = (const uint*)vb;
    ushort* Ys[4] = {Y0, Y1, Y2, Y3};
    #pragma unroll 4
    for (int rr = 0; rr < 4; ++rr) {
        const int b = off[(r0 + rr) * N_NODES + n];
        const int m = cnt[(r0 + rr) * N_NODES + n];
        float ax = 0.f, ay = 0.f;
        int i = 0;
        for (; i + 2 <= m; i += 2) {
            const int p0 = b + i, p1 = b + i + 1;
            const float e0 = evals[(size_t)p0 * 4 + hh];
            const float e1 = evals[(size_t)p1 * 4 + hh];
            const uint w0 = vb2[((size_t)srcS[p0] << 6) + lane];
            const uint w1 = vb2[((size_t)srcS[p1] << 6) + lane];
            ax = fmaf(e0, bf2f((ushort)(w0 & 0xffff)), ax);
            ay = fmaf(e0, bf2f((ushort)(w0 >> 16)), ay);
            ax = fmaf(e1, bf2f((ushort)(w1 & 0xffff)), ax);
            ay = fmaf(e1, bf2f((ushort)(w1 >> 16)), ay);
        }
        if (i < m) {
            const int p0 = b + i;
            const float e0 = evals[(size_t)p0 * 4 + hh];
            const uint w0 = vb2[((size_t)srcS[p0] << 6) + lane];
            ax = fmaf(e0, bf2f((ushort)(w0 & 0xffff)), ax);
            ay = fmaf(e0, bf2f((ushort)(w0 >> 16)), ay);
        }
        uint o = (uint)f2bf(ax * rden) | ((uint)f2bf(ay * rden) << 16);
        ((uint*)Ys[rr])[((size_t)n << 6) + lane] = o;
    }
}

// U = sum_{rr<4} Y_rr @ Wmsg[rr]. 16-node tiles (3200 blocks); each wave owns
// one head (wc). Fragment-order U per tile: Ut[jb2*1024 + i*256 + tid].
__global__ __launch_bounds__(256) void agg_gemm(
    const ushort* __restrict__ Y0, const ushort* __restrict__ Y1,
    const ushort* __restrict__ Y2, const ushort* __restrict__ Y3,
    const ushort* __restrict__ WmsgT, int r0, float* __restrict__ U)
{
    const int tid = threadIdx.x;
    const int n0 = blockIdx.x * 16;
    const int wc = tid >> 6;             // wave = head
    const int l = tid & 63;
    const int rc = l & 15, kg = (l >> 4) * 4;
    const ushort* Ys[4] = {Y0, Y1, Y2, Y3};
    const size_t arow = (size_t)(n0 + rc) * DIM;
    float* Ut = U + (size_t)blockIdx.x * 2048;

    bf16x8 af4[4];
    #pragma unroll
    for (int rr = 0; rr < 4; ++rr)
        af4[rr] = ldfrag(Ys[rr] + arow + wc*32 + kg);
    #pragma unroll
    for (int jb2 = 0; jb2 < 2; ++jb2) {
        const int jb = jb2 * 16;
        f32x4 acc = {0.f, 0.f, 0.f, 0.f};
        #pragma unroll
        for (int rr = 0; rr < 4; ++rr) {
            const ushort* Bcol = WmsgT + (size_t)(r0+rr)*4096 + wc*1024 + (size_t)(jb + rc) * 32 + kg;
            acc = __builtin_amdgcn_mfma_f32_16x16x32_bf16(af4[rr], ldfrag(Bcol), acc, 0, 0, 0);
        }
        #pragma unroll
        for (int i = 0; i < 4; ++i)
            Ut[jb2 * 1024 + i * 256 + tid] = acc[i];
    }
}

// Pass B fused with output projection. 16-node tiles (3200 blocks); wave = head
// in phase 1, wave = column quarter in phase 3. 8.4 KB LDS.
__global__ __launch_bounds__(256) void gemm_out(
    const ushort* __restrict__ Y0, const ushort* __restrict__ Y1,
    const ushort* __restrict__ Y2, const ushort* __restrict__ Y3,
    const ushort* __restrict__ WT, const float* __restrict__ U,
    const float* __restrict__ skip, float* __restrict__ outp, int r0)
{
    __shared__ float CsF[16 * 132];          // 8.4 KB; first 4 KB aliased as bf16 Ab
    ushort* Ab = (ushort*)CsF;
    const int tid = threadIdx.x;
    const int n0 = blockIdx.x * 16;
    const int t  = n0 / NODES_PER_TYPE;
    const int wc = tid >> 6;             // wave = head / col quarter
    const int l = tid & 63;
    const int rc = l & 15, g = l >> 4, kg = g * 4;
    const ushort* Ys[4] = {Y0, Y1, Y2, Y3};
    const size_t aoff = (size_t)(n0 + rc) * DIM;
    const float sg = 1.f / (1.f + expf(-skip[t]));
    const float* Ut = U + (size_t)blockIdx.x * 2048;

    // phase 1: finish U' (this wave: 16 rows x head-wc's 32 cols)
    f32x4 acc[2];
    bf16x8 af4[4];
    #pragma unroll
    for (int rr = 0; rr < 4; ++rr)
        af4[rr] = ldfrag(Ys[rr] + aoff + wc*32 + kg);
    #pragma unroll
    for (int jb2 = 0; jb2 < 2; ++jb2) {
        const int jb = jb2 * 16;
        #pragma unroll
        for (int i = 0; i < 4; ++i)
            acc[jb2][i] = Ut[jb2 * 1024 + i * 256 + tid];
        #pragma unroll
        for (int rr = 0; rr < 4; ++rr) {
            const ushort* Bcol = WT + 294912 + (size_t)(r0+rr)*4096 + wc*1024 + (size_t)(jb + rc) * 32 + kg;
            acc[jb2] = __builtin_amdgcn_mfma_f32_16x16x32_bf16(af4[rr], ldfrag(Bcol), acc[jb2], 0, 0, 0);
        }
    }

    // phase 2: acc -> bf16 swizzled Ab tile [16][128]
    #pragma unroll
    for (int jb2 = 0; jb2 < 2; ++jb2) {
        const int col = wc * 32 + jb2 * 16 + rc;
        #pragma unroll
        for (int i = 0; i < 4; ++i) {
            const int row = g * 4 + i;
            Ab[row * 128 + (col ^ ((row & 7) << 3))] = f2bf(acc[jb2][i]);
        }
    }
    __syncthreads();

    // phase 3: output projection; this wave computes cols wc*32..wc*32+31
    bf16x8 af[4];
    #pragma unroll
    for (int kt = 0; kt < 4; ++kt) af[kt] = ldsfragA(Ab, rc, kt * 32 + kg);
    const ushort* Wb = WT + 196608 + (size_t)t * 16384;
    f32x4 acc2[2];
    #pragma unroll
    for (int jb2 = 0; jb2 < 2; ++jb2) {
        acc2[jb2][0]=0.f; acc2[jb2][1]=0.f; acc2[jb2][2]=0.f; acc2[jb2][3]=0.f;
        const int colg = wc * 32 + jb2 * 16 + rc;
        const ushort* Bcol = Wb + (size_t)colg * 128 + kg;
        #pragma unroll
        for (int kt = 0; kt < 4; ++kt)
            acc2[jb2] = __builtin_amdgcn_mfma_f32_16x16x32_bf16(
                af[kt], ldfrag(Bcol + kt * 32), acc2[jb2], 0, 0, 0);
    }
    __syncthreads();   // Ab reads done before fp32 overwrite

    // phase 4: acc2*sg -> fp32 LDS [16][132] -> coalesced stores
    #pragma unroll
    for (int jb2 = 0; jb2 < 2; ++jb2) {
        const int col = wc * 32 + jb2 * 16 + rc;
        #pragma unroll
        for (int i = 0; i < 4; ++i)
            CsF[(g * 4 + i) * 132 + col] = sg * acc2[jb2][i];
    }
    __syncthreads();

    #pragma unroll
    for (int rd = 0; rd < 2; ++rd) {
        int f = tid + rd * 256;
        int row = f >> 5, c4 = (f & 31) * 4;
        float4 x = *(const float4*)&CsF[row * 132 + c4];
        *(float4*)(outp + (size_t)(n0 + row) * DIM + c4) = x;
    }
}

extern "C" void kernel_launch(void* const* d_in, const int* in_sizes, int n_in,
                              void* d_out, int out_size, void* d_ws, size_t ws_size,
                              hipStream_t stream) {
    (void)in_sizes; (void)n_in; (void)out_size; (void)ws_size;
    const float* h    = (const float*)d_in[0];
    const float* Wk   = (const float*)d_in[1];
    const float* Wq   = (const float*)d_in[2];
    const float* Wv   = (const float*)d_in[3];
    const float* Wa   = (const float*)d_in[4];
    const float* Watt = (const float*)d_in[5];
    const float* Wmsg = (const float*)d_in[6];
    const float* pri  = (const float*)d_in[7];
    const float* skip = (const float*)d_in[8];
    const int* row_idx = (const int*)d_in[9];
    const int* col_idx = (const int*)d_in[10];

    float* out = (float*)d_out;
    char*  wsb = (char*)d_ws;

    const size_t BF = (size_t)N_NODES * DIM * 2;   // 13.107 MB per bf16 node array
    // ws map (proven 8*BF = 104.86 MB):
    //  slot0: hb -> tfA0 (score) -> Y0 | slot1: kb -> Y1 | slot2: vb
    //  slot3: qb -> Y2 | slot4: tfb=tfA1 -> Y3
    //  slot5-6: tfA2, tfA3 (score phase) then U (fragment-order fp32, 26.2 MB)
    //  slot7: WT (0.66 MB)
    ushort* hb  = (ushort*)(wsb);
    ushort* kb  = (ushort*)(wsb + BF);
    ushort* vb  = (ushort*)(wsb + 2*BF);
    ushort* qb  = (ushort*)(wsb + 3*BF);
    ushort* tfb = (ushort*)(wsb + 4*BF);
    ushort* tf2 = (ushort*)(wsb + 5*BF);
    ushort* tf3 = (ushort*)(wsb + 6*BF);
    float*  U   = (float*) (wsb + 5*BF);
    ushort* WT  = (ushort*)(wsb + 7*BF);
    ushort* WattT = WT + 262144;
    ushort* WmsgT = WT + 294912;

    // d_out staging (fully consumed before gemm_out overwrites):
    float* evals = out;
    float* den   = out + (size_t)N_EDGES * N_HEADS;
    int*   cnt    = (int*)(den + (size_t)N_NODES * N_HEADS);
    int*   off    = cnt + (size_t)N_RELS * N_NODES;
    int*   bsum   = off + (size_t)N_RELS * N_NODES;
    int*   cursor = bsum + 1600;
    int*   srcS   = cursor + (size_t)N_RELS * N_NODES;
    int*   dstS   = srcS + N_EDGES;
    const int NBUCK = N_RELS * N_NODES;

    // 1. weight prep + h conversion + zero counts
    prep_weights<<<1280, 256, 0, stream>>>(Wk, Wq, Wv, Wa, Watt, Wmsg, WT);
    cvt_h<<<(N_NODES * DIM / 4) / 256, 256, 0, stream>>>(h, hb);
    zero_kernel<<<NBUCK / 4 / 256, 256, 0, stream>>>((float*)cnt, NBUCK / 4);
    // 2. fused K/Q/V projection
    proj_fused<<<N_NODES / 64, 256, 0, stream>>>(hb, WT, kb, qb, vb);
    // 3. CSR build + sorted src/dst
    hist_kernel<<<N_EDGES / 256, 256, 0, stream>>>(col_idx, cnt);
    scan1_kernel<<<NBUCK / 256, 256, 0, stream>>>(cnt, off, bsum);
    scan2_kernel<<<1, 256, 0, stream>>>(bsum, NBUCK / 256);
    scan3_kernel<<<NBUCK / 256, 256, 0, stream>>>(off, bsum, cursor);
    scatter_kernel<<<N_EDGES / 256, 256, 0, stream>>>(row_idx, col_idx, cursor, srcS, dstS);
    // 4. score phase: two 4-relation waves {trans4 -> wide score4}
    trans4<<<N_NODES / 64, 256, 0, stream>>>(qb, WattT, hb, tfb, tf2, tf3);
    score4<<<4 * (EDGES_PER_REL / 32), 256, 0, stream>>>(
        hb, tfb, tf2, tf3, kb, pri, srcS, dstS, evals, 0);
    trans4<<<N_NODES / 64, 256, 0, stream>>>(qb, WattT + 4 * 4096, hb, tfb, tf2, tf3);
    score4<<<4 * (EDGES_PER_REL / 32), 256, 0, stream>>>(
        hb, tfb, tf2, tf3, kb, pri, srcS, dstS, evals, 4);
    // 5. softmax denominators
    denom_pull<<<N_NODES * N_HEADS / 256, 256, 0, stream>>>(off, cnt, evals, den);
    // 6. aggregation: pass A -> U (16-node tiles); pass B + output projection -> out
    ypull<<<N_NODES / 4, 256, 0, stream>>>(vb, srcS, off, cnt, evals, den,
                                           hb, kb, qb, tfb, 0);
    agg_gemm<<<N_NODES / 16, 256, 0, stream>>>(hb, kb, qb, tfb, WmsgT, 0, U);
    ypull<<<N_NODES / 4, 256, 0, stream>>>(vb, srcS, off, cnt, evals, den,
                                           hb, kb, qb, tfb, 4);
    gemm_out<<<N_NODES / 16, 256, 0, stream>>>(hb, kb, qb, tfb, WT, U, skip, out, 4);
}